// Round 1
// baseline (702.037 us; speedup 1.0000x reference)
//
#include <hip/hip_runtime.h>
#include <stdint.h>

typedef __attribute__((ext_vector_type(8))) short s16x8;
typedef __attribute__((ext_vector_type(4))) float f32x4;

__device__ __forceinline__ ushort f2bf(float x) {
  union { float f; uint32_t u; } v; v.f = x;
  uint32_t r = v.u + 0x7FFFu + ((v.u >> 16) & 1u);
  return (ushort)(r >> 16);
}
__device__ __forceinline__ float bf2f(ushort u) {
  union { uint32_t u; float f; } v; v.u = ((uint32_t)u) << 16; return v.f;
}

// ---------------------------------------------------------------------------
// Weight prep: 10 slots of transposed bf16 weights [col][k] + f32 bias.
// slots: 0 q0, 1 q1, 2 kk_r0(kw1*att0), 3 kk_r1(kw0*att1), 4 kk_r2(kw0*att2),
//        5 vv_r0(vw1*msg0), 6 vv_r1(vw0*msg1), 7 vv_r2(vw0*msg2), 8 aw0, 9 aw1
// ---------------------------------------------------------------------------
__global__ __launch_bounds__(256) void prep_weights(
    const float* __restrict__ kw, const float* __restrict__ kb,
    const float* __restrict__ qw, const float* __restrict__ qb,
    const float* __restrict__ vw, const float* __restrict__ vb,
    const float* __restrict__ aw, const float* __restrict__ ab,
    const float* __restrict__ rel_att, const float* __restrict__ rel_msg,
    ushort* __restrict__ WT, float* __restrict__ BIAS)
{
  int slot = blockIdx.x, tid = threadIdx.x;
  const float* W; const float* b; const float* rel = nullptr;
  switch (slot) {
    case 0: W = qw;         b = qb;       break;
    case 1: W = qw + 16384; b = qb + 128; break;
    case 2: W = kw + 16384; b = kb + 128; rel = rel_att + 0*2048; break;
    case 3: W = kw;         b = kb;       rel = rel_att + 1*2048; break;
    case 4: W = kw;         b = kb;       rel = rel_att + 2*2048; break;
    case 5: W = vw + 16384; b = vb + 128; rel = rel_msg + 0*2048; break;
    case 6: W = vw;         b = vb;       rel = rel_msg + 1*2048; break;
    case 7: W = vw;         b = vb;       rel = rel_msg + 2*2048; break;
    case 8: W = aw;         b = ab;       break;
    default: W = aw + 16384; b = ab + 128; break;
  }
  ushort* out = WT + slot * 16384;
  for (int e = tid; e < 16384; e += 256) {
    int c = e >> 7, k = e & 127;
    float val;
    if (!rel) {
      val = W[k*128 + c];
    } else {
      int h = c >> 4, cc = c & 15;
      float s = 0.f;
      #pragma unroll
      for (int j = 0; j < 16; j++) s += W[k*128 + h*16 + j] * rel[h*256 + j*16 + cc];
      val = s;
    }
    out[c*128 + k] = f2bf(val);   // stored transposed: [col][k]
  }
  if (tid < 128) {
    int c = tid; float val;
    if (!rel) {
      val = b[c];
    } else {
      int h = c >> 4, cc = c & 15;
      float s = 0.f;
      #pragma unroll
      for (int j = 0; j < 16; j++) s += b[h*16 + j] * rel[h*256 + j*16 + cc];
      val = s;
    }
    BIAS[slot*128 + c] = val;
  }
}

// ---------------------------------------------------------------------------
// Projection GEMM: out_bf16[N][128] = bf16(f32 A[N][128]) @ W + bias
// 4 waves/block: wave = (rowsub, colhalf). No LDS, no barriers, B in regs.
// ---------------------------------------------------------------------------
__global__ __launch_bounds__(256) void proj_gemm(
    const float* __restrict__ h0, const float* __restrict__ h1,
    const ushort* __restrict__ WT, const float* __restrict__ BIAS,
    ushort* __restrict__ P, int N, int h1mask)
{
  int g = blockIdx.y;
  const float* A = ((h1mask >> g) & 1) ? h1 : h0;
  const ushort* Bt = WT + g * 16384;
  const float* bias = BIAS + g * 128;
  ushort* C = P + (size_t)g * N * 128;

  int tid = threadIdx.x;
  int lane = tid & 63;
  int wave = tid >> 6;
  int lr = lane & 15, lh = lane >> 4;
  int colbase = (wave & 1) * 64;
  int rowsub = wave >> 1;

  s16x8 bfr[4][4];
  #pragma unroll
  for (int ct = 0; ct < 4; ct++)
    #pragma unroll
    for (int ks = 0; ks < 4; ks++)
      bfr[ct][ks] = *(const s16x8*)(Bt + (colbase + ct*16 + lr)*128 + ks*32 + lh*8);
  float bv[4];
  #pragma unroll
  for (int ct = 0; ct < 4; ct++) bv[ct] = bias[colbase + ct*16 + lr];

  for (int base = blockIdx.x * 32; base < N; base += gridDim.x * 32) {
    int arow = base + rowsub*16 + lr;
    if (arow >= N) arow = N - 1;
    s16x8 af[4];
    #pragma unroll
    for (int ks = 0; ks < 4; ks++) {
      const float* ap = A + (size_t)arow*128 + ks*32 + lh*8;
      f32x4 x0 = *(const f32x4*)ap;
      f32x4 x1 = *(const f32x4*)(ap + 4);
      s16x8 v;
      #pragma unroll
      for (int j = 0; j < 4; j++) { v[j] = (short)f2bf(x0[j]); v[4+j] = (short)f2bf(x1[j]); }
      af[ks] = v;
    }
    #pragma unroll
    for (int ct = 0; ct < 4; ct++) {
      f32x4 acc = { bv[ct], bv[ct], bv[ct], bv[ct] };
      #pragma unroll
      for (int ks = 0; ks < 4; ks++)
        acc = __builtin_amdgcn_mfma_f32_16x16x32_bf16(af[ks], bfr[ct][ks], acc, 0, 0, 0);
      int col = colbase + ct*16 + lr;
      int r0 = base + rowsub*16 + lh*4;
      #pragma unroll
      for (int i = 0; i < 4; i++) {
        int r = r0 + i;
        if (r < N) C[(size_t)r*128 + col] = f2bf(acc[i]);
      }
    }
  }
}

// ---------------------------------------------------------------------------
// Final GEMM: out_f32 = (scale*agg) @ aw + ab, then skip-mix with h.
// ---------------------------------------------------------------------------
__global__ __launch_bounds__(256) void final_gemm(
    const float* __restrict__ agg, const float* __restrict__ h0,
    const float* __restrict__ h1,
    const ushort* __restrict__ WT, const float* __restrict__ BIAS,
    const float* __restrict__ skip,
    float* __restrict__ out, int N)
{
  int t = blockIdx.y;
  const float* A = agg + (size_t)t * N * 128;
  const float* H = t ? h1 : h0;
  float scale = t ? 1.0f : 0.5f;           // mean over 2 relations for type 0
  const ushort* Bt = WT + (8 + t) * 16384;
  const float* bias = BIAS + (8 + t) * 128;
  float alpha = 1.0f / (1.0f + __expf(-skip[t]));
  float beta = 1.0f - alpha;
  float* C = out + (size_t)t * N * 128;

  int tid = threadIdx.x;
  int lane = tid & 63;
  int wave = tid >> 6;
  int lr = lane & 15, lh = lane >> 4;
  int colbase = (wave & 1) * 64;
  int rowsub = wave >> 1;

  s16x8 bfr[4][4];
  #pragma unroll
  for (int ct = 0; ct < 4; ct++)
    #pragma unroll
    for (int ks = 0; ks < 4; ks++)
      bfr[ct][ks] = *(const s16x8*)(Bt + (colbase + ct*16 + lr)*128 + ks*32 + lh*8);
  float bv[4];
  #pragma unroll
  for (int ct = 0; ct < 4; ct++) bv[ct] = bias[colbase + ct*16 + lr];

  for (int base = blockIdx.x * 32; base < N; base += gridDim.x * 32) {
    int arow = base + rowsub*16 + lr;
    if (arow >= N) arow = N - 1;
    s16x8 af[4];
    #pragma unroll
    for (int ks = 0; ks < 4; ks++) {
      const float* ap = A + (size_t)arow*128 + ks*32 + lh*8;
      f32x4 x0 = *(const f32x4*)ap;
      f32x4 x1 = *(const f32x4*)(ap + 4);
      s16x8 v;
      #pragma unroll
      for (int j = 0; j < 4; j++) { v[j] = (short)f2bf(x0[j]*scale); v[4+j] = (short)f2bf(x1[j]*scale); }
      af[ks] = v;
    }
    #pragma unroll
    for (int ct = 0; ct < 4; ct++) {
      f32x4 acc = { bv[ct], bv[ct], bv[ct], bv[ct] };
      #pragma unroll
      for (int ks = 0; ks < 4; ks++)
        acc = __builtin_amdgcn_mfma_f32_16x16x32_bf16(af[ks], bfr[ct][ks], acc, 0, 0, 0);
      int col = colbase + ct*16 + lr;
      int r0 = base + rowsub*16 + lh*4;
      #pragma unroll
      for (int i = 0; i < 4; i++) {
        int r = r0 + i;
        if (r < N) {
          size_t off = (size_t)r*128 + col;
          C[off] = acc[i] * alpha + H[off] * beta;
        }
      }
    }
  }
}

// ---------------------------------------------------------------------------
// CSR build
// ---------------------------------------------------------------------------
__global__ void count_edges(const int* __restrict__ d0, const int* __restrict__ d1,
                            const int* __restrict__ d2, int* __restrict__ counts,
                            int E, int N)
{
  int idx = blockIdx.x * 256 + threadIdx.x;
  if (idx >= 3 * E) return;
  int r = idx / E, e = idx - r * E;
  const int* D = (r == 0) ? d0 : (r == 1) ? d1 : d2;
  atomicAdd(counts + r * N + D[e], 1);
}

__global__ __launch_bounds__(1024) void scan_counts(const int* __restrict__ counts,
                                                    int* __restrict__ offsets, int N)
{
  int r = blockIdx.x, tid = threadIdx.x;
  __shared__ int tmp[1024];
  __shared__ int carry_s;
  const int* c = counts + r * N;
  int* o = offsets + r * (N + 1);
  if (tid == 0) { o[0] = 0; carry_s = 0; }
  __syncthreads();
  for (int base = 0; base < N; base += 1024) {
    int i = base + tid;
    int v = (i < N) ? c[i] : 0;
    tmp[tid] = v;
    __syncthreads();
    for (int off = 1; off < 1024; off <<= 1) {
      int t = (tid >= off) ? tmp[tid - off] : 0;
      __syncthreads();
      tmp[tid] += t;
      __syncthreads();
    }
    if (i < N) o[i + 1] = carry_s + tmp[tid];
    __syncthreads();
    if (tid == 0) carry_s += tmp[1023];
    __syncthreads();
  }
}

__global__ void scatter_edges(const int* __restrict__ d0, const int* __restrict__ d1,
                              const int* __restrict__ d2,
                              const int* __restrict__ offsets, int* __restrict__ cursor,
                              int* __restrict__ elist, int E, int N)
{
  int idx = blockIdx.x * 256 + threadIdx.x;
  if (idx >= 3 * E) return;
  int r = idx / E, e = idx - r * E;
  const int* D = (r == 0) ? d0 : (r == 1) ? d1 : d2;
  int dst = D[e];
  int pos = offsets[r * (N + 1) + dst] + atomicAdd(cursor + r * N + dst, 1);
  elist[r * E + pos] = e;
}

// ---------------------------------------------------------------------------
// Per-(edge, head) attention scores
// ---------------------------------------------------------------------------
__global__ void edge_scores(const int* __restrict__ s0, const int* __restrict__ d0,
                            const int* __restrict__ s1, const int* __restrict__ d1,
                            const int* __restrict__ s2, const int* __restrict__ d2,
                            const ushort* __restrict__ P, const float* __restrict__ rel_pri,
                            float* __restrict__ scores, int E, int N)
{
  int idx = blockIdx.x * 256 + threadIdx.x;
  if (idx >= 3 * E * 8) return;
  int r = idx / (E * 8);
  int rem = idx - r * (E * 8);
  int e = rem >> 3, h = rem & 7;
  const int* S = (r == 0) ? s0 : (r == 1) ? s1 : s2;
  const int* D = (r == 0) ? d0 : (r == 1) ? d1 : d2;
  int src = S[e], dst = D[e];
  int dt = (r == 1) ? 1 : 0;
  const ushort* qrow = P + ((size_t)dt * N + dst) * 128 + h * 16;
  const ushort* krow = P + ((size_t)(2 + r) * N + src) * 128 + h * 16;
  s16x8 qa = *(const s16x8*)qrow;
  s16x8 qb_ = *(const s16x8*)(qrow + 8);
  s16x8 ka = *(const s16x8*)krow;
  s16x8 kb_ = *(const s16x8*)(krow + 8);
  float s = 0.f;
  #pragma unroll
  for (int j = 0; j < 8; j++) {
    s += bf2f((ushort)qa[j]) * bf2f((ushort)ka[j]);
    s += bf2f((ushort)qb_[j]) * bf2f((ushort)kb_[j]);
  }
  scores[(size_t)r * E * 8 + e * 8 + h] = s * rel_pri[r * 8 + h] * 0.25f;
}

// ---------------------------------------------------------------------------
// Per-(dst, head) softmax + weighted V aggregation (one relation per launch)
// ---------------------------------------------------------------------------
__global__ void aggregate(const int* __restrict__ elist, const int* __restrict__ offs,
                          const int* __restrict__ S, const float* __restrict__ scores,
                          const ushort* __restrict__ VV, float* __restrict__ agg,
                          int N, int accumulate)
{
  int idx = blockIdx.x * 256 + threadIdx.x;
  if (idx >= N * 8) return;
  int dst = idx >> 3, h = idx & 7;
  int b0 = offs[dst], b1 = offs[dst + 1];
  float m = -1e30f;
  for (int i = b0; i < b1; i++) {
    float sc = scores[(size_t)elist[i] * 8 + h];
    m = fmaxf(m, sc);
  }
  float sum = 0.f;
  float acc[16];
  #pragma unroll
  for (int j = 0; j < 16; j++) acc[j] = 0.f;
  for (int i = b0; i < b1; i++) {
    int e = elist[i];
    float w = __expf(scores[(size_t)e * 8 + h] - m);
    sum += w;
    const ushort* vr = VV + (size_t)S[e] * 128 + h * 16;
    s16x8 v0 = *(const s16x8*)vr;
    s16x8 v1 = *(const s16x8*)(vr + 8);
    #pragma unroll
    for (int j = 0; j < 8; j++) {
      acc[j]     += w * bf2f((ushort)v0[j]);
      acc[8 + j] += w * bf2f((ushort)v1[j]);
    }
  }
  float inv = (b1 > b0) ? 1.0f / sum : 0.f;
  float* ag = agg + (size_t)dst * 128 + h * 16;
  if (accumulate) {
    #pragma unroll
    for (int j = 0; j < 16; j++) ag[j] += acc[j] * inv;
  } else {
    #pragma unroll
    for (int j = 0; j < 16; j++) ag[j] = acc[j] * inv;
  }
}

// ---------------------------------------------------------------------------
extern "C" void kernel_launch(void* const* d_in, const int* in_sizes, int n_in,
                              void* d_out, int out_size, void* d_ws, size_t ws_size,
                              hipStream_t stream)
{
  const float* h0      = (const float*)d_in[0];
  const float* h1      = (const float*)d_in[1];
  const float* kw      = (const float*)d_in[2];
  const float* kb      = (const float*)d_in[3];
  const float* qw      = (const float*)d_in[4];
  const float* qb      = (const float*)d_in[5];
  const float* vw      = (const float*)d_in[6];
  const float* vb      = (const float*)d_in[7];
  const float* aw      = (const float*)d_in[8];
  const float* ab      = (const float*)d_in[9];
  const float* rel_att = (const float*)d_in[10];
  const float* rel_msg = (const float*)d_in[11];
  const float* rel_pri = (const float*)d_in[12];
  const float* skip    = (const float*)d_in[13];
  const int* s0 = (const int*)d_in[14];
  const int* d0 = (const int*)d_in[15];
  const int* s1 = (const int*)d_in[16];
  const int* d1 = (const int*)d_in[17];
  const int* s2 = (const int*)d_in[18];
  const int* d2 = (const int*)d_in[19];

  int N = in_sizes[0] / 128;
  int E = in_sizes[14];

  char* w = (char*)d_ws;
  size_t o = 0;
  auto alloc = [&](size_t bytes) { size_t cur = o; o += (bytes + 255) / 256 * 256; return cur; };
  ushort* WT   = (ushort*)(w + alloc((size_t)10 * 16384 * 2));
  float*  BIAS = (float*) (w + alloc((size_t)10 * 128 * 4));
  ushort* P    = (ushort*)(w + alloc((size_t)8 * N * 128 * 2));
  float*  SC   = (float*) (w + alloc((size_t)3 * E * 8 * 4));
  int* counts  = (int*)   (w + alloc((size_t)3 * N * 4));
  int* cursor  = (int*)   (w + alloc((size_t)3 * N * 4));
  int* offs    = (int*)   (w + alloc((size_t)3 * (N + 1) * 4));
  int* elist   = (int*)   (w + alloc((size_t)3 * E * 4));
  float* agg   = (float*) (w + alloc((size_t)2 * N * 128 * 4));
  (void)ws_size; (void)n_in; (void)out_size;

  hipMemsetAsync(counts, 0, (size_t)3 * N * 4, stream);
  hipMemsetAsync(cursor, 0, (size_t)3 * N * 4, stream);

  prep_weights<<<10, 256, 0, stream>>>(kw, kb, qw, qb, vw, vb, aw, ab,
                                       rel_att, rel_msg, WT, BIAS);

  // slot->source: g in {1,2,5} read h1 (q1, kk_r0, vv_r0), rest read h0
  int h1mask = (1 << 1) | (1 << 2) | (1 << 5);
  proj_gemm<<<dim3(320, 8), 256, 0, stream>>>(h0, h1, WT, BIAS, P, N, h1mask);

  int egrid = (3 * E + 255) / 256;
  count_edges<<<egrid, 256, 0, stream>>>(d0, d1, d2, counts, E, N);
  scan_counts<<<3, 1024, 0, stream>>>(counts, offs, N);
  scatter_edges<<<egrid, 256, 0, stream>>>(d0, d1, d2, offs, cursor, elist, E, N);

  int sgrid = (3 * E * 8 + 255) / 256;
  edge_scores<<<sgrid, 256, 0, stream>>>(s0, d0, s1, d1, s2, d2, P, rel_pri, SC, E, N);

  int agrid = (N * 8 + 255) / 256;
  // r0: dst type 0 (write), r2: dst type 0 (accumulate), r1: dst type 1 (write)
  aggregate<<<agrid, 256, 0, stream>>>(elist + 0 * E, offs + 0 * (N + 1), s0,
                                       SC + (size_t)0 * E * 8, P + (size_t)5 * N * 128,
                                       agg, N, 0);
  aggregate<<<agrid, 256, 0, stream>>>(elist + 1 * E, offs + 1 * (N + 1), s1,
                                       SC + (size_t)1 * E * 8, P + (size_t)6 * N * 128,
                                       agg + (size_t)N * 128, N, 0);
  aggregate<<<agrid, 256, 0, stream>>>(elist + 2 * E, offs + 2 * (N + 1), s2,
                                       SC + (size_t)2 * E * 8, P + (size_t)7 * N * 128,
                                       agg, N, 1);

  final_gemm<<<dim3(640, 2), 256, 0, stream>>>(agg, h0, h1, WT, BIAS, skip,
                                               (float*)d_out, N);
}

// Round 2
// 538.561 us; speedup vs baseline: 1.3035x; 1.3035x over previous
//
#include <hip/hip_runtime.h>
#include <stdint.h>

typedef __attribute__((ext_vector_type(8))) short s16x8;
typedef __attribute__((ext_vector_type(4))) float f32x4;

__device__ __forceinline__ ushort f2bf(float x) {
  union { float f; uint32_t u; } v; v.f = x;
  uint32_t r = v.u + 0x7FFFu + ((v.u >> 16) & 1u);
  return (ushort)(r >> 16);
}
__device__ __forceinline__ float bf2f(ushort u) {
  union { uint32_t u; float f; } v; v.u = ((uint32_t)u) << 16; return v.f;
}

// ---------------------------------------------------------------------------
// Weight prep: 10 slots of transposed bf16 weights [col][k] + f32 bias.
// slots: 0 q0, 1 q1, 2 kk_r0(kw1*att0), 3 kk_r1(kw0*att1), 4 kk_r2(kw0*att2),
//        5 vv_r0(vw1*msg0), 6 vv_r1(vw0*msg1), 7 vv_r2(vw0*msg2), 8 aw0, 9 aw1
// ---------------------------------------------------------------------------
__global__ __launch_bounds__(256) void prep_weights(
    const float* __restrict__ kw, const float* __restrict__ kb,
    const float* __restrict__ qw, const float* __restrict__ qb,
    const float* __restrict__ vw, const float* __restrict__ vb,
    const float* __restrict__ aw, const float* __restrict__ ab,
    const float* __restrict__ rel_att, const float* __restrict__ rel_msg,
    ushort* __restrict__ WT, float* __restrict__ BIAS)
{
  int slot = blockIdx.x, tid = threadIdx.x;
  const float* W; const float* b; const float* rel = nullptr;
  switch (slot) {
    case 0: W = qw;         b = qb;       break;
    case 1: W = qw + 16384; b = qb + 128; break;
    case 2: W = kw + 16384; b = kb + 128; rel = rel_att + 0*2048; break;
    case 3: W = kw;         b = kb;       rel = rel_att + 1*2048; break;
    case 4: W = kw;         b = kb;       rel = rel_att + 2*2048; break;
    case 5: W = vw + 16384; b = vb + 128; rel = rel_msg + 0*2048; break;
    case 6: W = vw;         b = vb;       rel = rel_msg + 1*2048; break;
    case 7: W = vw;         b = vb;       rel = rel_msg + 2*2048; break;
    case 8: W = aw;         b = ab;       break;
    default: W = aw + 16384; b = ab + 128; break;
  }
  ushort* out = WT + slot * 16384;
  for (int e = tid; e < 16384; e += 256) {
    int c = e >> 7, k = e & 127;
    float val;
    if (!rel) {
      val = W[k*128 + c];
    } else {
      int h = c >> 4, cc = c & 15;
      float s = 0.f;
      #pragma unroll
      for (int j = 0; j < 16; j++) s += W[k*128 + h*16 + j] * rel[h*256 + j*16 + cc];
      val = s;
    }
    out[c*128 + k] = f2bf(val);   // stored transposed: [col][k]
  }
  if (tid < 128) {
    int c = tid; float val;
    if (!rel) {
      val = b[c];
    } else {
      int h = c >> 4, cc = c & 15;
      float s = 0.f;
      #pragma unroll
      for (int j = 0; j < 16; j++) s += b[h*16 + j] * rel[h*256 + j*16 + cc];
      val = s;
    }
    BIAS[slot*128 + c] = val;
  }
}

// ---------------------------------------------------------------------------
// Projection GEMM: out_bf16[N][128] = bf16(f32 A[N][128]) @ W + bias
// ---------------------------------------------------------------------------
__global__ __launch_bounds__(256) void proj_gemm(
    const float* __restrict__ h0, const float* __restrict__ h1,
    const ushort* __restrict__ WT, const float* __restrict__ BIAS,
    ushort* __restrict__ P, int N, int h1mask)
{
  int g = blockIdx.y;
  const float* A = ((h1mask >> g) & 1) ? h1 : h0;
  const ushort* Bt = WT + g * 16384;
  const float* bias = BIAS + g * 128;
  ushort* C = P + (size_t)g * N * 128;

  int tid = threadIdx.x;
  int lane = tid & 63;
  int wave = tid >> 6;
  int lr = lane & 15, lh = lane >> 4;
  int colbase = (wave & 1) * 64;
  int rowsub = wave >> 1;

  s16x8 bfr[4][4];
  #pragma unroll
  for (int ct = 0; ct < 4; ct++)
    #pragma unroll
    for (int ks = 0; ks < 4; ks++)
      bfr[ct][ks] = *(const s16x8*)(Bt + (colbase + ct*16 + lr)*128 + ks*32 + lh*8);
  float bv[4];
  #pragma unroll
  for (int ct = 0; ct < 4; ct++) bv[ct] = bias[colbase + ct*16 + lr];

  for (int base = blockIdx.x * 32; base < N; base += gridDim.x * 32) {
    int arow = base + rowsub*16 + lr;
    if (arow >= N) arow = N - 1;
    s16x8 af[4];
    #pragma unroll
    for (int ks = 0; ks < 4; ks++) {
      const float* ap = A + (size_t)arow*128 + ks*32 + lh*8;
      f32x4 x0 = *(const f32x4*)ap;
      f32x4 x1 = *(const f32x4*)(ap + 4);
      s16x8 v;
      #pragma unroll
      for (int j = 0; j < 4; j++) { v[j] = (short)f2bf(x0[j]); v[4+j] = (short)f2bf(x1[j]); }
      af[ks] = v;
    }
    #pragma unroll
    for (int ct = 0; ct < 4; ct++) {
      f32x4 acc = { bv[ct], bv[ct], bv[ct], bv[ct] };
      #pragma unroll
      for (int ks = 0; ks < 4; ks++)
        acc = __builtin_amdgcn_mfma_f32_16x16x32_bf16(af[ks], bfr[ct][ks], acc, 0, 0, 0);
      int col = colbase + ct*16 + lr;
      int r0 = base + rowsub*16 + lh*4;
      #pragma unroll
      for (int i = 0; i < 4; i++) {
        int r = r0 + i;
        if (r < N) C[(size_t)r*128 + col] = f2bf(acc[i]);
      }
    }
  }
}

// ---------------------------------------------------------------------------
// Final GEMM: out_f32 = (scale*agg) @ aw + ab, then skip-mix with h.
// ---------------------------------------------------------------------------
__global__ __launch_bounds__(256) void final_gemm(
    const float* __restrict__ agg, const float* __restrict__ h0,
    const float* __restrict__ h1,
    const ushort* __restrict__ WT, const float* __restrict__ BIAS,
    const float* __restrict__ skip,
    float* __restrict__ out, int N)
{
  int t = blockIdx.y;
  const float* A = agg + (size_t)t * N * 128;
  const float* H = t ? h1 : h0;
  float scale = t ? 1.0f : 0.5f;           // mean over 2 relations for type 0
  const ushort* Bt = WT + (8 + t) * 16384;
  const float* bias = BIAS + (8 + t) * 128;
  float alpha = 1.0f / (1.0f + __expf(-skip[t]));
  float beta = 1.0f - alpha;
  float* C = out + (size_t)t * N * 128;

  int tid = threadIdx.x;
  int lane = tid & 63;
  int wave = tid >> 6;
  int lr = lane & 15, lh = lane >> 4;
  int colbase = (wave & 1) * 64;
  int rowsub = wave >> 1;

  s16x8 bfr[4][4];
  #pragma unroll
  for (int ct = 0; ct < 4; ct++)
    #pragma unroll
    for (int ks = 0; ks < 4; ks++)
      bfr[ct][ks] = *(const s16x8*)(Bt + (colbase + ct*16 + lr)*128 + ks*32 + lh*8);
  float bv[4];
  #pragma unroll
  for (int ct = 0; ct < 4; ct++) bv[ct] = bias[colbase + ct*16 + lr];

  for (int base = blockIdx.x * 32; base < N; base += gridDim.x * 32) {
    int arow = base + rowsub*16 + lr;
    if (arow >= N) arow = N - 1;
    s16x8 af[4];
    #pragma unroll
    for (int ks = 0; ks < 4; ks++) {
      const float* ap = A + (size_t)arow*128 + ks*32 + lh*8;
      f32x4 x0 = *(const f32x4*)ap;
      f32x4 x1 = *(const f32x4*)(ap + 4);
      s16x8 v;
      #pragma unroll
      for (int j = 0; j < 4; j++) { v[j] = (short)f2bf(x0[j]*scale); v[4+j] = (short)f2bf(x1[j]*scale); }
      af[ks] = v;
    }
    #pragma unroll
    for (int ct = 0; ct < 4; ct++) {
      f32x4 acc = { bv[ct], bv[ct], bv[ct], bv[ct] };
      #pragma unroll
      for (int ks = 0; ks < 4; ks++)
        acc = __builtin_amdgcn_mfma_f32_16x16x32_bf16(af[ks], bfr[ct][ks], acc, 0, 0, 0);
      int col = colbase + ct*16 + lr;
      int r0 = base + rowsub*16 + lh*4;
      #pragma unroll
      for (int i = 0; i < 4; i++) {
        int r = r0 + i;
        if (r < N) {
          size_t off = (size_t)r*128 + col;
          C[off] = acc[i] * alpha + H[off] * beta;
        }
      }
    }
  }
}

// ---------------------------------------------------------------------------
// CSR build
// ---------------------------------------------------------------------------
__global__ void count_edges(const int* __restrict__ d0, const int* __restrict__ d1,
                            const int* __restrict__ d2, int* __restrict__ counts,
                            int E, int N)
{
  int idx = blockIdx.x * 256 + threadIdx.x;
  if (idx >= 3 * E) return;
  int r = idx / E, e = idx - r * E;
  const int* D = (r == 0) ? d0 : (r == 1) ? d1 : d2;
  atomicAdd(counts + r * N + D[e], 1);
}

// ---- hierarchical scan: partial -> block-sum scan -> carry add ------------
#define SCAN_CHUNK 2048
#define MAXC 1024

__global__ __launch_bounds__(256) void scan_partial(
    const int* __restrict__ counts, int* __restrict__ offsets,
    int* __restrict__ bsum, int N)
{
  int r = blockIdx.y, c = blockIdx.x, tid = threadIdx.x;
  const int* cnt = counts + (size_t)r * N;
  int* o = offsets + (size_t)r * (N + 1);
  int idx0 = c * SCAN_CHUNK + tid * 8;
  int p[8]; int run = 0;
  #pragma unroll
  for (int j = 0; j < 8; j++) {
    int v = (idx0 + j < N) ? cnt[idx0 + j] : 0;
    run += v; p[j] = run;
  }
  int lane = tid & 63, wid = tid >> 6;
  int x = run;
  #pragma unroll
  for (int off = 1; off < 64; off <<= 1) {
    int t = __shfl_up(x, off, 64);
    if (lane >= off) x += t;
  }
  __shared__ int wsum[4];
  if (lane == 63) wsum[wid] = x;
  __syncthreads();
  int woff = 0;
  for (int wph = 0; wph < wid; wph++) woff += wsum[wph];
  int texcl = woff + x - run;   // exclusive prefix for this thread within block
  #pragma unroll
  for (int j = 0; j < 8; j++)
    if (idx0 + j < N) o[idx0 + j + 1] = texcl + p[j];
  if (tid == 255) bsum[r * MAXC + c] = woff + x;   // block total
}

__global__ void scan_bsums(int* __restrict__ bsum, int nchunks)
{
  int r = blockIdx.x, lane = threadIdx.x;   // 64 threads
  int carry = 0;
  for (int base = 0; base < nchunks; base += 64) {
    int i = base + lane;
    int v0 = (i < nchunks) ? bsum[r * MAXC + i] : 0;
    int x = v0;
    #pragma unroll
    for (int off = 1; off < 64; off <<= 1) {
      int t = __shfl_up(x, off, 64);
      if (lane >= off) x += t;
    }
    if (i < nchunks) bsum[r * MAXC + i] = carry + x - v0;  // exclusive carry
    carry += __shfl(x, 63, 64);
  }
}

__global__ __launch_bounds__(256) void scan_add(
    int* __restrict__ offsets, const int* __restrict__ bsum, int N)
{
  int r = blockIdx.y, c = blockIdx.x, tid = threadIdx.x;
  int* o = offsets + (size_t)r * (N + 1);
  if (c == 0 && tid == 0) o[0] = 0;
  int add = bsum[r * MAXC + c];
  if (add == 0) return;
  int idx0 = c * SCAN_CHUNK + tid * 8;
  #pragma unroll
  for (int j = 0; j < 8; j++) {
    int i = idx0 + j;
    if (i < N) o[i + 1] += add;
  }
}

__global__ void scatter_edges(const int* __restrict__ d0, const int* __restrict__ d1,
                              const int* __restrict__ d2,
                              const int* __restrict__ offsets, int* __restrict__ cursor,
                              int* __restrict__ elist, int E, int N)
{
  int idx = blockIdx.x * 256 + threadIdx.x;
  if (idx >= 3 * E) return;
  int r = idx / E, e = idx - r * E;
  const int* D = (r == 0) ? d0 : (r == 1) ? d1 : d2;
  int dst = D[e];
  int pos = offsets[r * (N + 1) + dst] + atomicAdd(cursor + r * N + dst, 1);
  elist[r * E + pos] = e;
}

// ---------------------------------------------------------------------------
// Per-(edge, head) attention scores
// ---------------------------------------------------------------------------
__global__ void edge_scores(const int* __restrict__ s0, const int* __restrict__ d0,
                            const int* __restrict__ s1, const int* __restrict__ d1,
                            const int* __restrict__ s2, const int* __restrict__ d2,
                            const ushort* __restrict__ P, const float* __restrict__ rel_pri,
                            float* __restrict__ scores, int E, int N)
{
  int idx = blockIdx.x * 256 + threadIdx.x;
  if (idx >= 3 * E * 8) return;
  int r = idx / (E * 8);
  int rem = idx - r * (E * 8);
  int e = rem >> 3, h = rem & 7;
  const int* S = (r == 0) ? s0 : (r == 1) ? s1 : s2;
  const int* D = (r == 0) ? d0 : (r == 1) ? d1 : d2;
  int src = S[e], dst = D[e];
  int dt = (r == 1) ? 1 : 0;
  const ushort* qrow = P + ((size_t)dt * N + dst) * 128 + h * 16;
  const ushort* krow = P + ((size_t)(2 + r) * N + src) * 128 + h * 16;
  s16x8 qa = *(const s16x8*)qrow;
  s16x8 qb_ = *(const s16x8*)(qrow + 8);
  s16x8 ka = *(const s16x8*)krow;
  s16x8 kb_ = *(const s16x8*)(krow + 8);
  float s = 0.f;
  #pragma unroll
  for (int j = 0; j < 8; j++) {
    s += bf2f((ushort)qa[j]) * bf2f((ushort)ka[j]);
    s += bf2f((ushort)qb_[j]) * bf2f((ushort)kb_[j]);
  }
  scores[(size_t)r * E * 8 + e * 8 + h] = s * rel_pri[r * 8 + h] * 0.25f;
}

// ---------------------------------------------------------------------------
// Per-(dst, head) softmax + weighted V aggregation (one relation per launch)
// ---------------------------------------------------------------------------
__global__ void aggregate(const int* __restrict__ elist, const int* __restrict__ offs,
                          const int* __restrict__ S, const float* __restrict__ scores,
                          const ushort* __restrict__ VV, float* __restrict__ agg,
                          int N, int accumulate)
{
  int idx = blockIdx.x * 256 + threadIdx.x;
  if (idx >= N * 8) return;
  int dst = idx >> 3, h = idx & 7;
  int b0 = offs[dst], b1 = offs[dst + 1];
  float m = -1e30f;
  for (int i = b0; i < b1; i++) {
    float sc = scores[(size_t)elist[i] * 8 + h];
    m = fmaxf(m, sc);
  }
  float sum = 0.f;
  float acc[16];
  #pragma unroll
  for (int j = 0; j < 16; j++) acc[j] = 0.f;
  for (int i = b0; i < b1; i++) {
    int e = elist[i];
    float w = __expf(scores[(size_t)e * 8 + h] - m);
    sum += w;
    const ushort* vr = VV + (size_t)S[e] * 128 + h * 16;
    s16x8 v0 = *(const s16x8*)vr;
    s16x8 v1 = *(const s16x8*)(vr + 8);
    #pragma unroll
    for (int j = 0; j < 8; j++) {
      acc[j]     += w * bf2f((ushort)v0[j]);
      acc[8 + j] += w * bf2f((ushort)v1[j]);
    }
  }
  float inv = (b1 > b0) ? 1.0f / sum : 0.f;
  float* ag = agg + (size_t)dst * 128 + h * 16;
  if (accumulate) {
    #pragma unroll
    for (int j = 0; j < 16; j++) ag[j] += acc[j] * inv;
  } else {
    #pragma unroll
    for (int j = 0; j < 16; j++) ag[j] = acc[j] * inv;
  }
}

// ---------------------------------------------------------------------------
extern "C" void kernel_launch(void* const* d_in, const int* in_sizes, int n_in,
                              void* d_out, int out_size, void* d_ws, size_t ws_size,
                              hipStream_t stream)
{
  const float* h0      = (const float*)d_in[0];
  const float* h1      = (const float*)d_in[1];
  const float* kw      = (const float*)d_in[2];
  const float* kb      = (const float*)d_in[3];
  const float* qw      = (const float*)d_in[4];
  const float* qb      = (const float*)d_in[5];
  const float* vw      = (const float*)d_in[6];
  const float* vb      = (const float*)d_in[7];
  const float* aw      = (const float*)d_in[8];
  const float* ab      = (const float*)d_in[9];
  const float* rel_att = (const float*)d_in[10];
  const float* rel_msg = (const float*)d_in[11];
  const float* rel_pri = (const float*)d_in[12];
  const float* skip    = (const float*)d_in[13];
  const int* s0 = (const int*)d_in[14];
  const int* d0 = (const int*)d_in[15];
  const int* s1 = (const int*)d_in[16];
  const int* d1 = (const int*)d_in[17];
  const int* s2 = (const int*)d_in[18];
  const int* d2 = (const int*)d_in[19];

  int N = in_sizes[0] / 128;
  int E = in_sizes[14];

  char* w = (char*)d_ws;
  size_t o = 0;
  auto alloc = [&](size_t bytes) { size_t cur = o; o += (bytes + 255) / 256 * 256; return cur; };
  ushort* WT   = (ushort*)(w + alloc((size_t)10 * 16384 * 2));
  float*  BIAS = (float*) (w + alloc((size_t)10 * 128 * 4));
  ushort* P    = (ushort*)(w + alloc((size_t)8 * N * 128 * 2));
  float*  SC   = (float*) (w + alloc((size_t)3 * E * 8 * 4));
  int* counts  = (int*)   (w + alloc((size_t)3 * N * 4));
  int* cursor  = (int*)   (w + alloc((size_t)3 * N * 4));
  int* offs    = (int*)   (w + alloc((size_t)3 * (N + 1) * 4));
  int* elist   = (int*)   (w + alloc((size_t)3 * E * 4));
  int* bsum    = (int*)   (w + alloc((size_t)3 * MAXC * 4));
  float* agg   = (float*) (w + alloc((size_t)2 * N * 128 * 4));
  (void)ws_size; (void)n_in; (void)out_size;

  hipMemsetAsync(counts, 0, (size_t)3 * N * 4, stream);
  hipMemsetAsync(cursor, 0, (size_t)3 * N * 4, stream);

  prep_weights<<<10, 256, 0, stream>>>(kw, kb, qw, qb, vw, vb, aw, ab,
                                       rel_att, rel_msg, WT, BIAS);

  // slot->source: g in {1,2,5} read h1 (q1, kk_r0, vv_r0), rest read h0
  int h1mask = (1 << 1) | (1 << 2) | (1 << 5);
  proj_gemm<<<dim3(320, 8), 256, 0, stream>>>(h0, h1, WT, BIAS, P, N, h1mask);

  int egrid = (3 * E + 255) / 256;
  count_edges<<<egrid, 256, 0, stream>>>(d0, d1, d2, counts, E, N);

  int nchunks = (N + SCAN_CHUNK - 1) / SCAN_CHUNK;
  scan_partial<<<dim3(nchunks, 3), 256, 0, stream>>>(counts, offs, bsum, N);
  scan_bsums<<<3, 64, 0, stream>>>(bsum, nchunks);
  scan_add<<<dim3(nchunks, 3), 256, 0, stream>>>(offs, bsum, N);

  scatter_edges<<<egrid, 256, 0, stream>>>(d0, d1, d2, offs, cursor, elist, E, N);

  int sgrid = (3 * E * 8 + 255) / 256;
  edge_scores<<<sgrid, 256, 0, stream>>>(s0, d0, s1, d1, s2, d2, P, rel_pri, SC, E, N);

  int agrid = (N * 8 + 255) / 256;
  // r0: dst type 0 (write), r2: dst type 0 (accumulate), r1: dst type 1 (write)
  aggregate<<<agrid, 256, 0, stream>>>(elist + 0 * E, offs + 0 * (N + 1), s0,
                                       SC + (size_t)0 * E * 8, P + (size_t)5 * N * 128,
                                       agg, N, 0);
  aggregate<<<agrid, 256, 0, stream>>>(elist + 1 * E, offs + 1 * (N + 1), s1,
                                       SC + (size_t)1 * E * 8, P + (size_t)6 * N * 128,
                                       agg + (size_t)N * 128, N, 0);
  aggregate<<<agrid, 256, 0, stream>>>(elist + 2 * E, offs + 2 * (N + 1), s2,
                                       SC + (size_t)2 * E * 8, P + (size_t)7 * N * 128,
                                       agg, N, 1);

  final_gemm<<<dim3(640, 2), 256, 0, stream>>>(agg, h0, h1, WT, BIAS, skip,
                                               (float*)d_out, N);
}